// Round 3
// baseline (1716.960 us; speedup 1.0000x reference)
//
#include <hip/hip_runtime.h>
#include <hip/hip_bf16.h>
#include <cmath>

#define N_ENT  50000
#define N_RELS 16
#define N_EDGE 1000000
#define DIM    64
#define OUT_STRIDE 176

// ---------------------------------------------------------------------------
// K1: histogram of dst -> counts
// ---------------------------------------------------------------------------
__global__ void hist_kernel(const int* __restrict__ dst,
                            int* __restrict__ counts, int n) {
    int i = blockIdx.x * blockDim.x + threadIdx.x;
    if (i < n) atomicAdd(&counts[dst[i]], 1);
}

// ---------------------------------------------------------------------------
// K2: exclusive scan counts -> row_ptr (single block, 1024 threads)
// ---------------------------------------------------------------------------
__global__ void scan_kernel(const int* __restrict__ counts,
                            int* __restrict__ row_ptr, int n) {
    __shared__ int sums[1024];
    int t = threadIdx.x;
    int chunk = (n + 1023) / 1024;
    int start = t * chunk;
    int end = start + chunk; if (end > n) end = n;
    int s = 0;
    for (int i = start; i < end && i >= 0; ++i) s += counts[i];
    sums[t] = s;
    __syncthreads();
    for (int off = 1; off < 1024; off <<= 1) {
        int v = (t >= off) ? sums[t - off] : 0;
        __syncthreads();
        sums[t] += v;
        __syncthreads();
    }
    int prefix = (t == 0) ? 0 : sums[t - 1];
    for (int i = start; i < end; ++i) {
        row_ptr[i] = prefix;
        prefix += counts[i];
    }
    if (end == n) row_ptr[n] = prefix;
}

// ---------------------------------------------------------------------------
// K3a: proj[r][n][:] = ent[n][:] @ W_R[r]  (fp32 compute, bf16 store)
// W_r staged in LDS (16 KB/block; Ws[k*64+lane] is a 2-way bank alias = free).
// Registers stay small -> no scratch spill (round-2 failure mode).
// ---------------------------------------------------------------------------
__global__ void proj_kernel(const float* __restrict__ ent,
                            const float* __restrict__ W_R,
                            __hip_bfloat16* __restrict__ proj) {
    __shared__ float Ws[DIM * DIM];
    int r = blockIdx.x;
    const float* Wr = W_R + (size_t)r * DIM * DIM;
    for (int i = threadIdx.x; i < DIM * DIM; i += blockDim.x)
        Ws[i] = Wr[i];
    __syncthreads();

    int lane   = threadIdx.x & 63;
    int wave   = blockIdx.y * (blockDim.x >> 6) + (threadIdx.x >> 6);
    int nwaves = gridDim.y * (blockDim.x >> 6);

    __hip_bfloat16* projr = proj + (size_t)r * N_ENT * DIM;
    int chunk = (N_ENT + nwaves - 1) / nwaves;
    int beg = wave * chunk;
    int end = beg + chunk; if (end > N_ENT) end = N_ENT;
    if (beg >= end) return;

    int n = beg;
    for (; n + 4 <= end; n += 4) {
        float x0 = ent[(size_t)(n + 0) * DIM + lane];
        float x1 = ent[(size_t)(n + 1) * DIM + lane];
        float x2 = ent[(size_t)(n + 2) * DIM + lane];
        float x3 = ent[(size_t)(n + 3) * DIM + lane];
        float a0 = 0.f, a1 = 0.f, a2 = 0.f, a3 = 0.f;
#pragma unroll
        for (int k = 0; k < DIM; ++k) {
            float w = Ws[k * DIM + lane];
            a0 = fmaf(__shfl(x0, k, 64), w, a0);
            a1 = fmaf(__shfl(x1, k, 64), w, a1);
            a2 = fmaf(__shfl(x2, k, 64), w, a2);
            a3 = fmaf(__shfl(x3, k, 64), w, a3);
        }
        projr[(size_t)(n + 0) * DIM + lane] = __float2bfloat16(a0);
        projr[(size_t)(n + 1) * DIM + lane] = __float2bfloat16(a1);
        projr[(size_t)(n + 2) * DIM + lane] = __float2bfloat16(a2);
        projr[(size_t)(n + 3) * DIM + lane] = __float2bfloat16(a3);
    }
    for (; n < end; ++n) {
        float x = ent[(size_t)n * DIM + lane];
        float a = 0.f;
#pragma unroll
        for (int k = 0; k < DIM; ++k)
            a = fmaf(__shfl(x, k, 64), Ws[k * DIM + lane], a);
        projr[(size_t)n * DIM + lane] = __float2bfloat16(a);
    }
}

// ---------------------------------------------------------------------------
// K3b: per-edge attention logits, 8 edges per wave (8 lanes x bf16x8 per edge)
// -> 16 outstanding 16-B gathers per wave for latency hiding.
// tanh via fast exp: tanh(x) = 1 - 2/(e^{2x}+1).
// ---------------------------------------------------------------------------
__device__ inline void bf16x8_unpack(uint4 u, float* f) {
    f[0] = __uint_as_float((u.x & 0xffffu) << 16);
    f[1] = __uint_as_float(u.x & 0xffff0000u);
    f[2] = __uint_as_float((u.y & 0xffffu) << 16);
    f[3] = __uint_as_float(u.y & 0xffff0000u);
    f[4] = __uint_as_float((u.z & 0xffffu) << 16);
    f[5] = __uint_as_float(u.z & 0xffff0000u);
    f[6] = __uint_as_float((u.w & 0xffffu) << 16);
    f[7] = __uint_as_float(u.w & 0xffff0000u);
}

__global__ void att_edge_kernel(const __hip_bfloat16* __restrict__ proj,
                                const float* __restrict__ rel,
                                const int* __restrict__ src,
                                const int* __restrict__ dst,
                                const int* __restrict__ etype,
                                const int* __restrict__ row_ptr,
                                int* __restrict__ cursor,
                                float* __restrict__ att_csr,
                                int* __restrict__ src_csr,
                                int n_edge) {
    int tid  = blockIdx.x * blockDim.x + threadIdx.x;
    int lane = threadIdx.x & 63;
    int sub  = lane >> 3;          // edge slot 0..7 within wave
    int q    = lane & 7;           // 8-lane slice of the 64-dim row
    int e    = (tid >> 6) * 8 + sub;
    if (e >= n_edge) return;

    int s = src[e];
    int d = dst[e];
    int r = etype[e];

    const uint4* pt = (const uint4*)(proj + ((size_t)r * N_ENT + s) * DIM + q * 8);
    const uint4* ph = (const uint4*)(proj + ((size_t)r * N_ENT + d) * DIM + q * 8);
    uint4 ut = *pt;
    uint4 uh = *ph;
    const float4* relv = (const float4*)(rel + r * DIM + q * 8);
    float4 ra = relv[0], rb = relv[1];

    float tv[8], hv[8], rv[8];
    bf16x8_unpack(ut, tv);
    bf16x8_unpack(uh, hv);
    rv[0] = ra.x; rv[1] = ra.y; rv[2] = ra.z; rv[3] = ra.w;
    rv[4] = rb.x; rv[5] = rb.y; rv[6] = rb.z; rv[7] = rb.w;

    float prod = 0.f;
#pragma unroll
    for (int j = 0; j < 8; ++j) {
        float x   = hv[j] + rv[j];
        float e2x = __expf(2.f * x);
        float th  = 1.f - 2.f / (e2x + 1.f);
        prod = fmaf(tv[j], th, prod);
    }
    // reduce across the 8 lanes of this edge (lanes sub*8 .. sub*8+7)
    prod += __shfl_xor(prod, 1, 64);
    prod += __shfl_xor(prod, 2, 64);
    prod += __shfl_xor(prod, 4, 64);

    if (q == 0) {
        int pos = row_ptr[d] + atomicAdd(&cursor[d], 1);
        att_csr[pos] = prod;
        src_csr[pos] = s;
    }
}

// ---------------------------------------------------------------------------
// K4: edge softmax per dst node (one wave per node), in-place
// ---------------------------------------------------------------------------
__global__ void softmax_kernel(const int* __restrict__ row_ptr,
                               float* __restrict__ a_csr, int n_node) {
    int wid  = (blockIdx.x * blockDim.x + threadIdx.x) >> 6;
    int lane = threadIdx.x & 63;
    if (wid >= n_node) return;
    int start = row_ptr[wid], end = row_ptr[wid + 1];

    float m = -INFINITY;
    for (int i = start + lane; i < end; i += 64) m = fmaxf(m, a_csr[i]);
#pragma unroll
    for (int off = 32; off > 0; off >>= 1)
        m = fmaxf(m, __shfl_xor(m, off, 64));

    float ssum = 0.f;
    for (int i = start + lane; i < end; i += 64) {
        float e = expf(a_csr[i] - m);
        a_csr[i] = e;
        ssum += e;
    }
#pragma unroll
    for (int off = 32; off > 0; off >>= 1)
        ssum += __shfl_xor(ssum, off, 64);

    if (end > start) {
        float inv = 1.0f / ssum;
        for (int i = start + lane; i < end; i += 64) a_csr[i] *= inv;
    }
}

// ---------------------------------------------------------------------------
// K5: copy raw ent_embed into out[:, 0:64]
// ---------------------------------------------------------------------------
__global__ void copy_ent_kernel(const float* __restrict__ ent,
                                float* __restrict__ out, int total) {
    int i = blockIdx.x * blockDim.x + threadIdx.x;
    if (i >= total) return;
    int n = i >> 6, c = i & 63;
    out[(size_t)n * OUT_STRIDE + c] = ent[i];
}

// ---------------------------------------------------------------------------
// K6: bi-interaction layer (one wave per node), edge loop unrolled x4 for MLP
// ---------------------------------------------------------------------------
template <int D_IN, int D_OUT>
__global__ void layer_kernel(const float* __restrict__ h_in,
                             const float* __restrict__ W1,
                             const float* __restrict__ b1,
                             const float* __restrict__ W2,
                             const float* __restrict__ b2,
                             const int* __restrict__ row_ptr,
                             const float* __restrict__ a_csr,
                             const int* __restrict__ src_csr,
                             float* __restrict__ h_out,   // may be null
                             float* __restrict__ out_buf,
                             int out_col, int n_node) {
    int wid  = (blockIdx.x * blockDim.x + threadIdx.x) >> 6;
    int lane = threadIdx.x & 63;
    if (wid >= n_node) return;

    float hval = (lane < D_IN) ? h_in[(size_t)wid * D_IN + lane] : 0.f;

    int start = row_ptr[wid], end = row_ptr[wid + 1];
    float acc0 = 0.f, acc1 = 0.f, acc2 = 0.f, acc3 = 0.f;
    int p = start;
    for (; p + 4 <= end; p += 4) {
        float av0 = a_csr[p + 0];
        float av1 = a_csr[p + 1];
        float av2 = a_csr[p + 2];
        float av3 = a_csr[p + 3];
        int   s0 = src_csr[p + 0];
        int   s1 = src_csr[p + 1];
        int   s2 = src_csr[p + 2];
        int   s3 = src_csr[p + 3];
        float h0 = (lane < D_IN) ? h_in[(size_t)s0 * D_IN + lane] : 0.f;
        float h1 = (lane < D_IN) ? h_in[(size_t)s1 * D_IN + lane] : 0.f;
        float h2 = (lane < D_IN) ? h_in[(size_t)s2 * D_IN + lane] : 0.f;
        float h3 = (lane < D_IN) ? h_in[(size_t)s3 * D_IN + lane] : 0.f;
        acc0 = fmaf(av0, h0, acc0);
        acc1 = fmaf(av1, h1, acc1);
        acc2 = fmaf(av2, h2, acc2);
        acc3 = fmaf(av3, h3, acc3);
    }
    for (; p < end; ++p) {
        float av = a_csr[p];
        int   si = src_csr[p];
        float hs = (lane < D_IN) ? h_in[(size_t)si * D_IN + lane] : 0.f;
        acc0 = fmaf(av, hs, acc0);
    }
    float acc = (acc0 + acc1) + (acc2 + acc3);

    float u = hval + acc;
    float v = hval * acc;

    float o1 = (lane < D_OUT) ? b1[lane] : 0.f;
    float o2 = (lane < D_OUT) ? b2[lane] : 0.f;
#pragma unroll
    for (int k = 0; k < D_IN; ++k) {
        float uk = __shfl(u, k, 64);
        float vk = __shfl(v, k, 64);
        if (lane < D_OUT) {
            o1 = fmaf(uk, W1[k * D_OUT + lane], o1);
            o2 = fmaf(vk, W2[k * D_OUT + lane], o2);
        }
    }
    float r1 = (o1 >= 0.f) ? o1 : 0.01f * o1;
    float r2 = (o2 >= 0.f) ? o2 : 0.01f * o2;
    float res = (lane < D_OUT) ? (r1 + r2) : 0.f;

    float sq = res * res;
#pragma unroll
    for (int off = 32; off > 0; off >>= 1)
        sq += __shfl_xor(sq, off, 64);
    float nrm  = sqrtf(sq);
    float resn = res / fmaxf(nrm, 1e-12f);

    if (lane < D_OUT) {
        if (h_out) h_out[(size_t)wid * D_OUT + lane] = res;
        out_buf[(size_t)wid * OUT_STRIDE + out_col + lane] = resn;
    }
}

// ---------------------------------------------------------------------------
extern "C" void kernel_launch(void* const* d_in, const int* in_sizes, int n_in,
                              void* d_out, int out_size, void* d_ws, size_t ws_size,
                              hipStream_t stream) {
    const float* ent  = (const float*)d_in[0];
    const float* rel  = (const float*)d_in[1];
    const float* W_R  = (const float*)d_in[2];
    const float* W1_0 = (const float*)d_in[3];
    const float* b1_0 = (const float*)d_in[4];
    const float* W2_0 = (const float*)d_in[5];
    const float* b2_0 = (const float*)d_in[6];
    const float* W1_1 = (const float*)d_in[7];
    const float* b1_1 = (const float*)d_in[8];
    const float* W2_1 = (const float*)d_in[9];
    const float* b2_1 = (const float*)d_in[10];
    const float* W1_2 = (const float*)d_in[11];
    const float* b1_2 = (const float*)d_in[12];
    const float* W2_2 = (const float*)d_in[13];
    const float* b2_2 = (const float*)d_in[14];
    const int*   src   = (const int*)d_in[15];
    const int*   dst   = (const int*)d_in[16];
    const int*   etype = (const int*)d_in[17];
    float* out = (float*)d_out;

    // workspace layout
    char* w = (char*)d_ws;
    float* att_csr = (float*)w;  w += (size_t)N_EDGE * 4;          // 4 MB
    int*   src_csr = (int*)w;    w += (size_t)N_EDGE * 4;          // 4 MB
    int*   counts  = (int*)w;    w += (size_t)(N_ENT + 64) * 4;
    int*   row_ptr = (int*)w;    w += (size_t)(N_ENT + 64) * 4;
    int*   cursor  = (int*)w;    w += (size_t)(N_ENT + 64) * 4;
    float* h1      = (float*)w;  w += (size_t)N_ENT * 64 * 4;      // 12.8 MB
    float* h2      = (float*)w;  w += (size_t)N_ENT * 32 * 4;      // 6.4 MB
    __hip_bfloat16* proj = (__hip_bfloat16*)w;
    size_t need = (size_t)(w - (char*)d_ws) + (size_t)N_RELS * N_ENT * DIM * 2;

    hipMemsetAsync(counts, 0, (size_t)N_ENT * 4, stream);
    hipMemsetAsync(cursor, 0, (size_t)N_ENT * 4, stream);

    hist_kernel<<<(N_EDGE + 255) / 256, 256, 0, stream>>>(dst, counts, N_EDGE);
    scan_kernel<<<1, 1024, 0, stream>>>(counts, row_ptr, N_ENT);

    if (ws_size >= need) {
        // fast path: precompute proj (W in LDS), then 8-edges-per-wave pass
        proj_kernel<<<dim3(N_RELS, 64), 256, 0, stream>>>(ent, W_R, proj);
        att_edge_kernel<<<((N_EDGE + 7) / 8 * 64 + 255) / 256, 256, 0, stream>>>(
            proj, rel, src, dst, etype, row_ptr, cursor, att_csr, src_csr, N_EDGE);
    } else {
        // fallback: should not trigger (need ~130 MB)
        proj_kernel<<<dim3(N_RELS, 64), 256, 0, stream>>>(ent, W_R, (__hip_bfloat16*)h1);
        att_edge_kernel<<<((N_EDGE + 7) / 8 * 64 + 255) / 256, 256, 0, stream>>>(
            (__hip_bfloat16*)h1, rel, src, dst, etype, row_ptr, cursor, att_csr, src_csr, N_EDGE);
    }

    softmax_kernel<<<(N_ENT + 3) / 4, 256, 0, stream>>>(row_ptr, att_csr, N_ENT);
    copy_ent_kernel<<<(N_ENT * DIM + 255) / 256, 256, 0, stream>>>(ent, out, N_ENT * DIM);

    layer_kernel<64, 64><<<(N_ENT + 3) / 4, 256, 0, stream>>>(
        ent, W1_0, b1_0, W2_0, b2_0, row_ptr, att_csr, src_csr, h1, out, 64, N_ENT);
    layer_kernel<64, 32><<<(N_ENT + 3) / 4, 256, 0, stream>>>(
        h1, W1_1, b1_1, W2_1, b2_1, row_ptr, att_csr, src_csr, h2, out, 128, N_ENT);
    layer_kernel<32, 16><<<(N_ENT + 3) / 4, 256, 0, stream>>>(
        h2, W1_2, b1_2, W2_2, b2_2, row_ptr, att_csr, src_csr, nullptr, out, 160, N_ENT);
}

// Round 4
// 729.416 us; speedup vs baseline: 2.3539x; 2.3539x over previous
//
#include <hip/hip_runtime.h>
#include <hip/hip_bf16.h>
#include <cmath>

#define N_ENT  50000
#define N_RELS 16
#define N_EDGE 1000000
#define DIM    64
#define OUT_STRIDE 176

typedef float f32x4 __attribute__((ext_vector_type(4)));
typedef short s16x8 __attribute__((ext_vector_type(8)));

// ---------------------------------------------------------------------------
// K0a: convert ent fp32 -> bf16
// ---------------------------------------------------------------------------
__global__ __launch_bounds__(256) void ent2bf16_kernel(
        const float* __restrict__ ent, ushort* __restrict__ ent_bf, int total) {
    int i = blockIdx.x * blockDim.x + threadIdx.x;
    if (i < total) {
        __hip_bfloat16 b = __float2bfloat16(ent[i]);
        ent_bf[i] = *(ushort*)&b;
    }
}

// ---------------------------------------------------------------------------
// K1: histogram of dst -> counts
// ---------------------------------------------------------------------------
__global__ __launch_bounds__(256) void hist_kernel(
        const int* __restrict__ dst, int* __restrict__ counts, int n) {
    int i = blockIdx.x * blockDim.x + threadIdx.x;
    if (i < n) atomicAdd(&counts[dst[i]], 1);
}

// ---------------------------------------------------------------------------
// K2: exclusive scan counts -> row_ptr (single block, 1024 threads)
// ---------------------------------------------------------------------------
__global__ __launch_bounds__(1024) void scan_kernel(
        const int* __restrict__ counts, int* __restrict__ row_ptr, int n) {
    __shared__ int sums[1024];
    int t = threadIdx.x;
    int chunk = (n + 1023) / 1024;
    int start = t * chunk;
    int end = start + chunk; if (end > n) end = n;
    int s = 0;
    for (int i = start; i < end && i >= 0; ++i) s += counts[i];
    sums[t] = s;
    __syncthreads();
    for (int off = 1; off < 1024; off <<= 1) {
        int v = (t >= off) ? sums[t - off] : 0;
        __syncthreads();
        sums[t] += v;
        __syncthreads();
    }
    int prefix = (t == 0) ? 0 : sums[t - 1];
    for (int i = start; i < end; ++i) {
        row_ptr[i] = prefix;
        prefix += counts[i];
    }
    if (end == n) row_ptr[n] = prefix;
}

// ---------------------------------------------------------------------------
// K3a: proj[r] = ent @ W_R[r] via bf16 MFMA (fp32 accum, bf16 store).
// One wave computes 16x64 output tiles; B fragments loaded once per wave.
// Layouts (m89/m91/m120-verified):
//   A[m][k]:  m = lane&15, k = (lane>>4)*8 + j   (j = 0..7, one 16B load)
//   B[k][n]:  n = lane&15, k = (lane>>4)*8 + j
//   C/D:      col = lane&15, row = (lane>>4)*4 + reg
// ---------------------------------------------------------------------------
__global__ __launch_bounds__(256) void proj_mfma_kernel(
        const ushort* __restrict__ ent_bf,     // [N_ENT][64] bf16
        const float*  __restrict__ W_R,        // [16][64][64] fp32
        __hip_bfloat16* __restrict__ proj) {   // [16][N_ENT][64] bf16
    int lane = threadIdx.x & 63;
    int m    = lane & 15;
    int q    = lane >> 4;
    int r    = blockIdx.y;
    int wid  = blockIdx.x * (blockDim.x >> 6) + (threadIdx.x >> 6);
    int nw   = gridDim.x * (blockDim.x >> 6);

    // load B fragments (4 col tiles x 2 k-chunks), convert fp32 -> bf16
    const float* Wr = W_R + (size_t)r * DIM * DIM;
    s16x8 bfrag[4][2];
#pragma unroll
    for (int c = 0; c < 4; ++c)
#pragma unroll
        for (int ch = 0; ch < 2; ++ch)
#pragma unroll
            for (int j = 0; j < 8; ++j) {
                __hip_bfloat16 b = __float2bfloat16(Wr[(ch * 32 + q * 8 + j) * DIM + c * 16 + m]);
                bfrag[c][ch][j] = *(short*)&b;
            }

    __hip_bfloat16* projr = proj + (size_t)r * N_ENT * DIM;
    const int ntiles = N_ENT / 16;             // 3125 exactly

    for (int t = wid; t < ntiles; t += nw) {
        int row0 = t * 16;
        const s16x8* arow = (const s16x8*)(ent_bf + (size_t)(row0 + m) * DIM);
        s16x8 a0 = arow[q];        // k-chunk 0: k = q*8 .. q*8+7
        s16x8 a1 = arow[4 + q];    // k-chunk 1: k = 32 + q*8 ..
        f32x4 acc[4];
#pragma unroll
        for (int c = 0; c < 4; ++c) acc[c] = (f32x4){0.f, 0.f, 0.f, 0.f};
#pragma unroll
        for (int c = 0; c < 4; ++c) {
            acc[c] = __builtin_amdgcn_mfma_f32_16x16x32_bf16(a0, bfrag[c][0], acc[c], 0, 0, 0);
            acc[c] = __builtin_amdgcn_mfma_f32_16x16x32_bf16(a1, bfrag[c][1], acc[c], 0, 0, 0);
        }
        __hip_bfloat16* prow = projr + (size_t)row0 * DIM;
#pragma unroll
        for (int c = 0; c < 4; ++c)
#pragma unroll
            for (int i = 0; i < 4; ++i)
                prow[(q * 4 + i) * DIM + c * 16 + m] = __float2bfloat16(acc[c][i]);
    }
}

// ---------------------------------------------------------------------------
// K3b: per-edge attention logits, 8 edges per wave (8 lanes x bf16x8 per edge)
// tanh via fast exp: tanh(x) = 1 - 2/(e^{2x}+1).
// ---------------------------------------------------------------------------
__device__ inline void bf16x8_unpack(uint4 u, float* f) {
    f[0] = __uint_as_float((u.x & 0xffffu) << 16);
    f[1] = __uint_as_float(u.x & 0xffff0000u);
    f[2] = __uint_as_float((u.y & 0xffffu) << 16);
    f[3] = __uint_as_float(u.y & 0xffff0000u);
    f[4] = __uint_as_float((u.z & 0xffffu) << 16);
    f[5] = __uint_as_float(u.z & 0xffff0000u);
    f[6] = __uint_as_float((u.w & 0xffffu) << 16);
    f[7] = __uint_as_float(u.w & 0xffff0000u);
}

__global__ __launch_bounds__(256) void att_edge_kernel(
        const __hip_bfloat16* __restrict__ proj,
        const float* __restrict__ rel,
        const int* __restrict__ src,
        const int* __restrict__ dst,
        const int* __restrict__ etype,
        const int* __restrict__ row_ptr,
        int* __restrict__ cursor,
        float* __restrict__ att_csr,
        int* __restrict__ src_csr,
        int n_edge) {
    int tid  = blockIdx.x * blockDim.x + threadIdx.x;
    int lane = threadIdx.x & 63;
    int sub  = lane >> 3;
    int q    = lane & 7;
    int e    = (tid >> 6) * 8 + sub;
    if (e >= n_edge) return;

    int s = src[e];
    int d = dst[e];
    int r = etype[e];

    const uint4* pt = (const uint4*)(proj + ((size_t)r * N_ENT + s) * DIM + q * 8);
    const uint4* ph = (const uint4*)(proj + ((size_t)r * N_ENT + d) * DIM + q * 8);
    uint4 ut = *pt;
    uint4 uh = *ph;
    const float4* relv = (const float4*)(rel + r * DIM + q * 8);
    float4 ra = relv[0], rb = relv[1];

    float tv[8], hv[8], rv[8];
    bf16x8_unpack(ut, tv);
    bf16x8_unpack(uh, hv);
    rv[0] = ra.x; rv[1] = ra.y; rv[2] = ra.z; rv[3] = ra.w;
    rv[4] = rb.x; rv[5] = rb.y; rv[6] = rb.z; rv[7] = rb.w;

    float prod = 0.f;
#pragma unroll
    for (int j = 0; j < 8; ++j) {
        float x   = hv[j] + rv[j];
        float e2x = __expf(2.f * x);
        float th  = 1.f - 2.f / (e2x + 1.f);
        prod = fmaf(tv[j], th, prod);
    }
    prod += __shfl_xor(prod, 1, 64);
    prod += __shfl_xor(prod, 2, 64);
    prod += __shfl_xor(prod, 4, 64);

    if (q == 0) {
        int pos = row_ptr[d] + atomicAdd(&cursor[d], 1);
        att_csr[pos] = prod;
        src_csr[pos] = s;
    }
}

// ---------------------------------------------------------------------------
// K3-fallback (ws too small; shouldn't trigger): per-edge fp32 matvec
// ---------------------------------------------------------------------------
__global__ __launch_bounds__(256) void att_kernel(
        const float* __restrict__ ent,
        const float* __restrict__ rel,
        const float* __restrict__ W_R,
        const int* __restrict__ src,
        const int* __restrict__ dst,
        const int* __restrict__ etype,
        const int* __restrict__ row_ptr,
        int* __restrict__ cursor,
        float* __restrict__ att_csr,
        int* __restrict__ src_csr,
        int n_edge) {
    int wid  = (blockIdx.x * blockDim.x + threadIdx.x) >> 6;
    int lane = threadIdx.x & 63;
    if (wid >= n_edge) return;
    int s = src[wid], d = dst[wid], r = etype[wid];
    const float* Wr = W_R + (size_t)r * DIM * DIM;
    float et = ent[(size_t)s * DIM + lane];
    float eh = ent[(size_t)d * DIM + lane];
    float acc_t = 0.f, acc_h = 0.f;
#pragma unroll
    for (int k = 0; k < DIM; ++k) {
        float w  = Wr[k * DIM + lane];
        acc_t = fmaf(__shfl(et, k, 64), w, acc_t);
        acc_h = fmaf(__shfl(eh, k, 64), w, acc_h);
    }
    float xx = acc_h + rel[r * DIM + lane];
    float e2x = __expf(2.f * xx);
    float th  = 1.f - 2.f / (e2x + 1.f);
    float prod = acc_t * th;
#pragma unroll
    for (int off = 32; off > 0; off >>= 1)
        prod += __shfl_down(prod, off, 64);
    if (lane == 0) {
        int pos = row_ptr[d] + atomicAdd(&cursor[d], 1);
        att_csr[pos] = prod;
        src_csr[pos] = s;
    }
}

// ---------------------------------------------------------------------------
// K4: edge softmax per dst node (one wave per node), in-place
// ---------------------------------------------------------------------------
__global__ __launch_bounds__(256) void softmax_kernel(
        const int* __restrict__ row_ptr, float* __restrict__ a_csr, int n_node) {
    int wid  = (blockIdx.x * blockDim.x + threadIdx.x) >> 6;
    int lane = threadIdx.x & 63;
    if (wid >= n_node) return;
    int start = row_ptr[wid], end = row_ptr[wid + 1];

    float m = -INFINITY;
    for (int i = start + lane; i < end; i += 64) m = fmaxf(m, a_csr[i]);
#pragma unroll
    for (int off = 32; off > 0; off >>= 1)
        m = fmaxf(m, __shfl_xor(m, off, 64));

    float ssum = 0.f;
    for (int i = start + lane; i < end; i += 64) {
        float e = expf(a_csr[i] - m);
        a_csr[i] = e;
        ssum += e;
    }
#pragma unroll
    for (int off = 32; off > 0; off >>= 1)
        ssum += __shfl_xor(ssum, off, 64);

    if (end > start) {
        float inv = 1.0f / ssum;
        for (int i = start + lane; i < end; i += 64) a_csr[i] *= inv;
    }
}

// ---------------------------------------------------------------------------
// K5: copy raw ent_embed into out[:, 0:64]
// ---------------------------------------------------------------------------
__global__ __launch_bounds__(256) void copy_ent_kernel(
        const float* __restrict__ ent, float* __restrict__ out, int total) {
    int i = blockIdx.x * blockDim.x + threadIdx.x;
    if (i >= total) return;
    int n = i >> 6, c = i & 63;
    out[(size_t)n * OUT_STRIDE + c] = ent[i];
}

// ---------------------------------------------------------------------------
// K6: bi-interaction layer (one wave per node), edge loop unrolled x4
// ---------------------------------------------------------------------------
template <int D_IN, int D_OUT>
__global__ __launch_bounds__(256) void layer_kernel(
        const float* __restrict__ h_in,
        const float* __restrict__ W1,
        const float* __restrict__ b1,
        const float* __restrict__ W2,
        const float* __restrict__ b2,
        const int* __restrict__ row_ptr,
        const float* __restrict__ a_csr,
        const int* __restrict__ src_csr,
        float* __restrict__ h_out,   // may be null
        float* __restrict__ out_buf,
        int out_col, int n_node) {
    int wid  = (blockIdx.x * blockDim.x + threadIdx.x) >> 6;
    int lane = threadIdx.x & 63;
    if (wid >= n_node) return;

    float hval = (lane < D_IN) ? h_in[(size_t)wid * D_IN + lane] : 0.f;

    int start = row_ptr[wid], end = row_ptr[wid + 1];
    float acc0 = 0.f, acc1 = 0.f, acc2 = 0.f, acc3 = 0.f;
    int p = start;
    for (; p + 4 <= end; p += 4) {
        float av0 = a_csr[p + 0];
        float av1 = a_csr[p + 1];
        float av2 = a_csr[p + 2];
        float av3 = a_csr[p + 3];
        int   s0 = src_csr[p + 0];
        int   s1 = src_csr[p + 1];
        int   s2 = src_csr[p + 2];
        int   s3 = src_csr[p + 3];
        float h0 = (lane < D_IN) ? h_in[(size_t)s0 * D_IN + lane] : 0.f;
        float h1 = (lane < D_IN) ? h_in[(size_t)s1 * D_IN + lane] : 0.f;
        float h2 = (lane < D_IN) ? h_in[(size_t)s2 * D_IN + lane] : 0.f;
        float h3 = (lane < D_IN) ? h_in[(size_t)s3 * D_IN + lane] : 0.f;
        acc0 = fmaf(av0, h0, acc0);
        acc1 = fmaf(av1, h1, acc1);
        acc2 = fmaf(av2, h2, acc2);
        acc3 = fmaf(av3, h3, acc3);
    }
    for (; p < end; ++p) {
        float av = a_csr[p];
        int   si = src_csr[p];
        float hs = (lane < D_IN) ? h_in[(size_t)si * D_IN + lane] : 0.f;
        acc0 = fmaf(av, hs, acc0);
    }
    float acc = (acc0 + acc1) + (acc2 + acc3);

    float u = hval + acc;
    float v = hval * acc;

    float o1 = (lane < D_OUT) ? b1[lane] : 0.f;
    float o2 = (lane < D_OUT) ? b2[lane] : 0.f;
#pragma unroll
    for (int k = 0; k < D_IN; ++k) {
        float uk = __shfl(u, k, 64);
        float vk = __shfl(v, k, 64);
        if (lane < D_OUT) {
            o1 = fmaf(uk, W1[k * D_OUT + lane], o1);
            o2 = fmaf(vk, W2[k * D_OUT + lane], o2);
        }
    }
    float r1 = (o1 >= 0.f) ? o1 : 0.01f * o1;
    float r2 = (o2 >= 0.f) ? o2 : 0.01f * o2;
    float res = (lane < D_OUT) ? (r1 + r2) : 0.f;

    float sq = res * res;
#pragma unroll
    for (int off = 32; off > 0; off >>= 1)
        sq += __shfl_xor(sq, off, 64);
    float nrm  = sqrtf(sq);
    float resn = res / fmaxf(nrm, 1e-12f);

    if (lane < D_OUT) {
        if (h_out) h_out[(size_t)wid * D_OUT + lane] = res;
        out_buf[(size_t)wid * OUT_STRIDE + out_col + lane] = resn;
    }
}

// ---------------------------------------------------------------------------
extern "C" void kernel_launch(void* const* d_in, const int* in_sizes, int n_in,
                              void* d_out, int out_size, void* d_ws, size_t ws_size,
                              hipStream_t stream) {
    const float* ent  = (const float*)d_in[0];
    const float* rel  = (const float*)d_in[1];
    const float* W_R  = (const float*)d_in[2];
    const float* W1_0 = (const float*)d_in[3];
    const float* b1_0 = (const float*)d_in[4];
    const float* W2_0 = (const float*)d_in[5];
    const float* b2_0 = (const float*)d_in[6];
    const float* W1_1 = (const float*)d_in[7];
    const float* b1_1 = (const float*)d_in[8];
    const float* W2_1 = (const float*)d_in[9];
    const float* b2_1 = (const float*)d_in[10];
    const float* W1_2 = (const float*)d_in[11];
    const float* b1_2 = (const float*)d_in[12];
    const float* W2_2 = (const float*)d_in[13];
    const float* b2_2 = (const float*)d_in[14];
    const int*   src   = (const int*)d_in[15];
    const int*   dst   = (const int*)d_in[16];
    const int*   etype = (const int*)d_in[17];
    float* out = (float*)d_out;

    // workspace layout
    char* w = (char*)d_ws;
    float* att_csr = (float*)w;  w += (size_t)N_EDGE * 4;          // 4 MB
    int*   src_csr = (int*)w;    w += (size_t)N_EDGE * 4;          // 4 MB
    int*   counts  = (int*)w;    w += (size_t)(N_ENT + 64) * 4;
    int*   row_ptr = (int*)w;    w += (size_t)(N_ENT + 64) * 4;
    int*   cursor  = (int*)w;    w += (size_t)(N_ENT + 64) * 4;
    float* h1      = (float*)w;  w += (size_t)N_ENT * 64 * 4;      // 12.8 MB
    float* h2      = (float*)w;  w += (size_t)N_ENT * 32 * 4;      // 6.4 MB
    ushort* ent_bf = (ushort*)w; w += (size_t)N_ENT * DIM * 2;     // 6.4 MB
    __hip_bfloat16* proj = (__hip_bfloat16*)w;
    size_t need = (size_t)(w - (char*)d_ws) + (size_t)N_RELS * N_ENT * DIM * 2;

    hipMemsetAsync(counts, 0, (size_t)N_ENT * 4, stream);
    hipMemsetAsync(cursor, 0, (size_t)N_ENT * 4, stream);

    hist_kernel<<<(N_EDGE + 255) / 256, 256, 0, stream>>>(dst, counts, N_EDGE);
    scan_kernel<<<1, 1024, 0, stream>>>(counts, row_ptr, N_ENT);

    if (ws_size >= need) {
        ent2bf16_kernel<<<(N_ENT * DIM + 255) / 256, 256, 0, stream>>>(
            ent, ent_bf, N_ENT * DIM);
        proj_mfma_kernel<<<dim3(64, N_RELS), 256, 0, stream>>>(ent_bf, W_R, proj);
        att_edge_kernel<<<((N_EDGE + 7) / 8 * 64 + 255) / 256, 256, 0, stream>>>(
            proj, rel, src, dst, etype, row_ptr, cursor, att_csr, src_csr, N_EDGE);
    } else {
        att_kernel<<<(N_EDGE + 3) / 4, 256, 0, stream>>>(
            ent, rel, W_R, src, dst, etype, row_ptr, cursor, att_csr, src_csr, N_EDGE);
    }

    softmax_kernel<<<(N_ENT + 3) / 4, 256, 0, stream>>>(row_ptr, att_csr, N_ENT);
    copy_ent_kernel<<<(N_ENT * DIM + 255) / 256, 256, 0, stream>>>(ent, out, N_ENT * DIM);

    layer_kernel<64, 64><<<(N_ENT + 3) / 4, 256, 0, stream>>>(
        ent, W1_0, b1_0, W2_0, b2_0, row_ptr, att_csr, src_csr, h1, out, 64, N_ENT);
    layer_kernel<64, 32><<<(N_ENT + 3) / 4, 256, 0, stream>>>(
        h1, W1_1, b1_1, W2_1, b2_1, row_ptr, att_csr, src_csr, h2, out, 128, N_ENT);
    layer_kernel<32, 16><<<(N_ENT + 3) / 4, 256, 0, stream>>>(
        h2, W1_2, b1_2, W2_2, b2_2, row_ptr, att_csr, src_csr, nullptr, out, 160, N_ENT);
}

// Round 5
// 675.606 us; speedup vs baseline: 2.5414x; 1.0796x over previous
//
#include <hip/hip_runtime.h>
#include <hip/hip_bf16.h>
#include <cmath>

#define N_ENT  50000
#define N_RELS 16
#define N_EDGE 1000000
#define DIM    64
#define OUT_STRIDE 176

typedef float f32x4 __attribute__((ext_vector_type(4)));
typedef short s16x8 __attribute__((ext_vector_type(8)));

__device__ inline void bf16x8_unpack(uint4 u, float* f) {
    f[0] = __uint_as_float((u.x & 0xffffu) << 16);
    f[1] = __uint_as_float(u.x & 0xffff0000u);
    f[2] = __uint_as_float((u.y & 0xffffu) << 16);
    f[3] = __uint_as_float(u.y & 0xffff0000u);
    f[4] = __uint_as_float((u.z & 0xffffu) << 16);
    f[5] = __uint_as_float(u.z & 0xffff0000u);
    f[6] = __uint_as_float((u.w & 0xffffu) << 16);
    f[7] = __uint_as_float(u.w & 0xffff0000u);
}

// ---------------------------------------------------------------------------
// K0a: convert ent fp32 -> bf16
// ---------------------------------------------------------------------------
__global__ __launch_bounds__(256) void ent2bf16_kernel(
        const float* __restrict__ ent, ushort* __restrict__ ent_bf, int total) {
    int i = blockIdx.x * blockDim.x + threadIdx.x;
    if (i < total) {
        __hip_bfloat16 b = __float2bfloat16(ent[i]);
        ent_bf[i] = *(ushort*)&b;
    }
}

// ---------------------------------------------------------------------------
// K1: histogram of dst -> counts
// ---------------------------------------------------------------------------
__global__ __launch_bounds__(256) void hist_kernel(
        const int* __restrict__ dst, int* __restrict__ counts, int n) {
    int i = blockIdx.x * blockDim.x + threadIdx.x;
    if (i < n) atomicAdd(&counts[dst[i]], 1);
}

// ---------------------------------------------------------------------------
// K2: exclusive scan counts -> row_ptr (single block, 1024 threads)
// ---------------------------------------------------------------------------
__global__ __launch_bounds__(1024) void scan_kernel(
        const int* __restrict__ counts, int* __restrict__ row_ptr, int n) {
    __shared__ int sums[1024];
    int t = threadIdx.x;
    int chunk = (n + 1023) / 1024;
    int start = t * chunk;
    int end = start + chunk; if (end > n) end = n;
    int s = 0;
    for (int i = start; i < end && i >= 0; ++i) s += counts[i];
    sums[t] = s;
    __syncthreads();
    for (int off = 1; off < 1024; off <<= 1) {
        int v = (t >= off) ? sums[t - off] : 0;
        __syncthreads();
        sums[t] += v;
        __syncthreads();
    }
    int prefix = (t == 0) ? 0 : sums[t - 1];
    for (int i = start; i < end; ++i) {
        row_ptr[i] = prefix;
        prefix += counts[i];
    }
    if (end == n) row_ptr[n] = prefix;
}

// ---------------------------------------------------------------------------
// K3a: proj[r] = ent @ W_R[r] via bf16 MFMA (fp32 accum, bf16 store).
// ---------------------------------------------------------------------------
__global__ __launch_bounds__(256) void proj_mfma_kernel(
        const ushort* __restrict__ ent_bf,     // [N_ENT][64] bf16
        const float*  __restrict__ W_R,        // [16][64][64] fp32
        __hip_bfloat16* __restrict__ proj) {   // [16][N_ENT][64] bf16
    int lane = threadIdx.x & 63;
    int m    = lane & 15;
    int q    = lane >> 4;
    int r    = blockIdx.y;
    int wid  = blockIdx.x * (blockDim.x >> 6) + (threadIdx.x >> 6);
    int nw   = gridDim.x * (blockDim.x >> 6);

    const float* Wr = W_R + (size_t)r * DIM * DIM;
    s16x8 bfrag[4][2];
#pragma unroll
    for (int c = 0; c < 4; ++c)
#pragma unroll
        for (int ch = 0; ch < 2; ++ch)
#pragma unroll
            for (int j = 0; j < 8; ++j) {
                __hip_bfloat16 b = __float2bfloat16(Wr[(ch * 32 + q * 8 + j) * DIM + c * 16 + m]);
                bfrag[c][ch][j] = *(short*)&b;
            }

    __hip_bfloat16* projr = proj + (size_t)r * N_ENT * DIM;
    const int ntiles = N_ENT / 16;             // 3125 exactly

    for (int t = wid; t < ntiles; t += nw) {
        int row0 = t * 16;
        const s16x8* arow = (const s16x8*)(ent_bf + (size_t)(row0 + m) * DIM);
        s16x8 a0 = arow[q];
        s16x8 a1 = arow[4 + q];
        f32x4 acc[4];
#pragma unroll
        for (int c = 0; c < 4; ++c) acc[c] = (f32x4){0.f, 0.f, 0.f, 0.f};
#pragma unroll
        for (int c = 0; c < 4; ++c) {
            acc[c] = __builtin_amdgcn_mfma_f32_16x16x32_bf16(a0, bfrag[c][0], acc[c], 0, 0, 0);
            acc[c] = __builtin_amdgcn_mfma_f32_16x16x32_bf16(a1, bfrag[c][1], acc[c], 0, 0, 0);
        }
        __hip_bfloat16* prow = projr + (size_t)row0 * DIM;
#pragma unroll
        for (int c = 0; c < 4; ++c)
#pragma unroll
            for (int i = 0; i < 4; ++i)
                prow[(q * 4 + i) * DIM + c * 16 + m] = __float2bfloat16(acc[c][i]);
    }
}

// ---------------------------------------------------------------------------
// K3b: per-edge attention logits, 8 edges per wave.
// ---------------------------------------------------------------------------
__global__ __launch_bounds__(256) void att_edge_kernel(
        const __hip_bfloat16* __restrict__ proj,
        const float* __restrict__ rel,
        const int* __restrict__ src,
        const int* __restrict__ dst,
        const int* __restrict__ etype,
        const int* __restrict__ row_ptr,
        int* __restrict__ cursor,
        float* __restrict__ att_csr,
        int* __restrict__ src_csr,
        int n_edge) {
    int tid  = blockIdx.x * blockDim.x + threadIdx.x;
    int lane = threadIdx.x & 63;
    int sub  = lane >> 3;
    int q    = lane & 7;
    int e    = (tid >> 6) * 8 + sub;
    if (e >= n_edge) return;

    int s = src[e];
    int d = dst[e];
    int r = etype[e];

    const uint4* pt = (const uint4*)(proj + ((size_t)r * N_ENT + s) * DIM + q * 8);
    const uint4* ph = (const uint4*)(proj + ((size_t)r * N_ENT + d) * DIM + q * 8);
    uint4 ut = *pt;
    uint4 uh = *ph;
    const float4* relv = (const float4*)(rel + r * DIM + q * 8);
    float4 ra = relv[0], rb = relv[1];

    float tv[8], hv[8], rv[8];
    bf16x8_unpack(ut, tv);
    bf16x8_unpack(uh, hv);
    rv[0] = ra.x; rv[1] = ra.y; rv[2] = ra.z; rv[3] = ra.w;
    rv[4] = rb.x; rv[5] = rb.y; rv[6] = rb.z; rv[7] = rb.w;

    float prod = 0.f;
#pragma unroll
    for (int j = 0; j < 8; ++j) {
        float x   = hv[j] + rv[j];
        float e2x = __expf(2.f * x);
        float th  = 1.f - 2.f / (e2x + 1.f);
        prod = fmaf(tv[j], th, prod);
    }
    prod += __shfl_xor(prod, 1, 64);
    prod += __shfl_xor(prod, 2, 64);
    prod += __shfl_xor(prod, 4, 64);

    if (q == 0) {
        int pos = row_ptr[d] + atomicAdd(&cursor[d], 1);
        att_csr[pos] = prod;
        src_csr[pos] = s;
    }
}

// ---------------------------------------------------------------------------
// K3-fallback (ws too small; shouldn't trigger)
// ---------------------------------------------------------------------------
__global__ __launch_bounds__(256) void att_kernel(
        const float* __restrict__ ent,
        const float* __restrict__ rel,
        const float* __restrict__ W_R,
        const int* __restrict__ src,
        const int* __restrict__ dst,
        const int* __restrict__ etype,
        const int* __restrict__ row_ptr,
        int* __restrict__ cursor,
        float* __restrict__ att_csr,
        int* __restrict__ src_csr,
        int n_edge) {
    int wid  = (blockIdx.x * blockDim.x + threadIdx.x) >> 6;
    int lane = threadIdx.x & 63;
    if (wid >= n_edge) return;
    int s = src[wid], d = dst[wid], r = etype[wid];
    const float* Wr = W_R + (size_t)r * DIM * DIM;
    float et = ent[(size_t)s * DIM + lane];
    float eh = ent[(size_t)d * DIM + lane];
    float acc_t = 0.f, acc_h = 0.f;
#pragma unroll
    for (int k = 0; k < DIM; ++k) {
        float w  = Wr[k * DIM + lane];
        acc_t = fmaf(__shfl(et, k, 64), w, acc_t);
        acc_h = fmaf(__shfl(eh, k, 64), w, acc_h);
    }
    float xx = acc_h + rel[r * DIM + lane];
    float e2x = __expf(2.f * xx);
    float th  = 1.f - 2.f / (e2x + 1.f);
    float prod = acc_t * th;
#pragma unroll
    for (int off = 32; off > 0; off >>= 1)
        prod += __shfl_down(prod, off, 64);
    if (lane == 0) {
        int pos = row_ptr[d] + atomicAdd(&cursor[d], 1);
        att_csr[pos] = prod;
        src_csr[pos] = s;
    }
}

// ---------------------------------------------------------------------------
// K4: edge softmax per dst node (one wave per node), in-place
// ---------------------------------------------------------------------------
__global__ __launch_bounds__(256) void softmax_kernel(
        const int* __restrict__ row_ptr, float* __restrict__ a_csr, int n_node) {
    int wid  = (blockIdx.x * blockDim.x + threadIdx.x) >> 6;
    int lane = threadIdx.x & 63;
    if (wid >= n_node) return;
    int start = row_ptr[wid], end = row_ptr[wid + 1];

    float m = -INFINITY;
    for (int i = start + lane; i < end; i += 64) m = fmaxf(m, a_csr[i]);
#pragma unroll
    for (int off = 32; off > 0; off >>= 1)
        m = fmaxf(m, __shfl_xor(m, off, 64));

    float ssum = 0.f;
    for (int i = start + lane; i < end; i += 64) {
        float e = expf(a_csr[i] - m);
        a_csr[i] = e;
        ssum += e;
    }
#pragma unroll
    for (int off = 32; off > 0; off >>= 1)
        ssum += __shfl_xor(ssum, off, 64);

    if (end > start) {
        float inv = 1.0f / ssum;
        for (int i = start + lane; i < end; i += 64) a_csr[i] *= inv;
    }
}

// ---------------------------------------------------------------------------
// K5: copy raw ent_embed into out[:, 0:64]
// ---------------------------------------------------------------------------
__global__ __launch_bounds__(256) void copy_ent_kernel(
        const float* __restrict__ ent, float* __restrict__ out, int total) {
    int i = blockIdx.x * blockDim.x + threadIdx.x;
    if (i >= total) return;
    int n = i >> 6, c = i & 63;
    out[(size_t)n * OUT_STRIDE + c] = ent[i];
}

// ---------------------------------------------------------------------------
// K6: bi-interaction layer v2 (one wave per node, bf16 gathers, slot layout).
// LPR = lanes per h-row (D_IN/8), SLOTS = 64/LPR edges in flight.
// Lane (q=lane%LPR, sub=lane/LPR) holds dims q*8..q*8+7 of edge-slot sub.
// ---------------------------------------------------------------------------
template <int D_IN, int D_OUT>
__global__ __launch_bounds__(256) void layer_kernel(
        const ushort* __restrict__ h_bf,      // [N][D_IN] bf16
        const float* __restrict__ W1,
        const float* __restrict__ b1,
        const float* __restrict__ W2,
        const float* __restrict__ b2,
        const int* __restrict__ row_ptr,
        const float* __restrict__ a_csr,
        const int* __restrict__ src_csr,
        ushort* __restrict__ h_out_bf,        // may be null; [N][D_OUT] bf16
        float* __restrict__ out_buf,
        int out_col, int n_node) {
    constexpr int LPR   = D_IN / 8;           // 8 (D_IN=64) or 4 (D_IN=32)
    constexpr int SLOTS = 64 / LPR;           // 8 or 16

    int wid  = (blockIdx.x * blockDim.x + threadIdx.x) >> 6;
    int lane = threadIdx.x & 63;
    if (wid >= n_node) return;
    int q   = lane & (LPR - 1);
    int sub = lane / LPR;

    // own row (replicated across slots)
    uint4 uown = *(const uint4*)(h_bf + (size_t)wid * D_IN + q * 8);
    float hv[8];
    bf16x8_unpack(uown, hv);

    int start = row_ptr[wid], end = row_ptr[wid + 1];
    float acc[8];
#pragma unroll
    for (int j = 0; j < 8; ++j) acc[j] = 0.f;

    for (int p = start + sub; p < end; p += SLOTS) {
        float av = a_csr[p];
        int   si = src_csr[p];
        uint4 u  = *(const uint4*)(h_bf + (size_t)si * D_IN + q * 8);
        float g[8];
        bf16x8_unpack(u, g);
#pragma unroll
        for (int j = 0; j < 8; ++j) acc[j] = fmaf(av, g[j], acc[j]);
    }
    // combine edge slots (xor over lane bits >= log2(LPR))
#pragma unroll
    for (int mask = LPR; mask < 64; mask <<= 1)
#pragma unroll
        for (int j = 0; j < 8; ++j)
            acc[j] += __shfl_xor(acc[j], mask, 64);

    float uu[8], vv[8];
#pragma unroll
    for (int j = 0; j < 8; ++j) {
        uu[j] = hv[j] + acc[j];
        vv[j] = hv[j] * acc[j];
    }

    float o1 = (lane < D_OUT) ? b1[lane] : 0.f;
    float o2 = (lane < D_OUT) ? b2[lane] : 0.f;
#pragma unroll
    for (int k = 0; k < D_IN; ++k) {
        float uk = __shfl(uu[k & 7], k >> 3, 64);   // source: lane k/8 (sub=0)
        float vk = __shfl(vv[k & 7], k >> 3, 64);
        if (lane < D_OUT) {
            o1 = fmaf(uk, W1[k * D_OUT + lane], o1);
            o2 = fmaf(vk, W2[k * D_OUT + lane], o2);
        }
    }
    float r1 = (o1 >= 0.f) ? o1 : 0.01f * o1;
    float r2 = (o2 >= 0.f) ? o2 : 0.01f * o2;
    float res = (lane < D_OUT) ? (r1 + r2) : 0.f;

    float sq = res * res;
#pragma unroll
    for (int off = 32; off > 0; off >>= 1)
        sq += __shfl_xor(sq, off, 64);
    float nrm  = sqrtf(sq);
    float resn = res / fmaxf(nrm, 1e-12f);

    if (lane < D_OUT) {
        if (h_out_bf) {
            __hip_bfloat16 b = __float2bfloat16(res);
            h_out_bf[(size_t)wid * D_OUT + lane] = *(ushort*)&b;
        }
        out_buf[(size_t)wid * OUT_STRIDE + out_col + lane] = resn;
    }
}

// ---------------------------------------------------------------------------
extern "C" void kernel_launch(void* const* d_in, const int* in_sizes, int n_in,
                              void* d_out, int out_size, void* d_ws, size_t ws_size,
                              hipStream_t stream) {
    const float* ent  = (const float*)d_in[0];
    const float* rel  = (const float*)d_in[1];
    const float* W_R  = (const float*)d_in[2];
    const float* W1_0 = (const float*)d_in[3];
    const float* b1_0 = (const float*)d_in[4];
    const float* W2_0 = (const float*)d_in[5];
    const float* b2_0 = (const float*)d_in[6];
    const float* W1_1 = (const float*)d_in[7];
    const float* b1_1 = (const float*)d_in[8];
    const float* W2_1 = (const float*)d_in[9];
    const float* b2_1 = (const float*)d_in[10];
    const float* W1_2 = (const float*)d_in[11];
    const float* b1_2 = (const float*)d_in[12];
    const float* W2_2 = (const float*)d_in[13];
    const float* b2_2 = (const float*)d_in[14];
    const int*   src   = (const int*)d_in[15];
    const int*   dst   = (const int*)d_in[16];
    const int*   etype = (const int*)d_in[17];
    float* out = (float*)d_out;

    // workspace layout (all region sizes multiples of 16 B)
    char* w = (char*)d_ws;
    float*  att_csr = (float*)w;  w += (size_t)N_EDGE * 4;          // 4 MB
    int*    src_csr = (int*)w;    w += (size_t)N_EDGE * 4;          // 4 MB
    int*    counts  = (int*)w;    w += (size_t)(N_ENT + 64) * 4;
    int*    row_ptr = (int*)w;    w += (size_t)(N_ENT + 64) * 4;
    int*    cursor  = (int*)w;    w += (size_t)(N_ENT + 64) * 4;
    ushort* ent_bf  = (ushort*)w; w += (size_t)N_ENT * 64 * 2;      // 6.4 MB
    ushort* h1_bf   = (ushort*)w; w += (size_t)N_ENT * 64 * 2;      // 6.4 MB
    ushort* h2_bf   = (ushort*)w; w += (size_t)N_ENT * 32 * 2;      // 3.2 MB
    __hip_bfloat16* proj = (__hip_bfloat16*)w;
    size_t need = (size_t)(w - (char*)d_ws) + (size_t)N_RELS * N_ENT * DIM * 2;

    hipMemsetAsync(counts, 0, (size_t)N_ENT * 4, stream);
    hipMemsetAsync(cursor, 0, (size_t)N_ENT * 4, stream);

    hist_kernel<<<(N_EDGE + 255) / 256, 256, 0, stream>>>(dst, counts, N_EDGE);
    scan_kernel<<<1, 1024, 0, stream>>>(counts, row_ptr, N_ENT);
    ent2bf16_kernel<<<(N_ENT * DIM + 255) / 256, 256, 0, stream>>>(
        ent, ent_bf, N_ENT * DIM);

    if (ws_size >= need) {
        proj_mfma_kernel<<<dim3(64, N_RELS), 256, 0, stream>>>(ent_bf, W_R, proj);
        att_edge_kernel<<<((N_EDGE + 7) / 8 * 64 + 255) / 256, 256, 0, stream>>>(
            proj, rel, src, dst, etype, row_ptr, cursor, att_csr, src_csr, N_EDGE);
    } else {
        att_kernel<<<(N_EDGE + 3) / 4, 256, 0, stream>>>(
            ent, rel, W_R, src, dst, etype, row_ptr, cursor, att_csr, src_csr, N_EDGE);
    }

    softmax_kernel<<<(N_ENT + 3) / 4, 256, 0, stream>>>(row_ptr, att_csr, N_ENT);
    copy_ent_kernel<<<(N_ENT * DIM + 255) / 256, 256, 0, stream>>>(ent, out, N_ENT * DIM);

    layer_kernel<64, 64><<<(N_ENT + 3) / 4, 256, 0, stream>>>(
        ent_bf, W1_0, b1_0, W2_0, b2_0, row_ptr, att_csr, src_csr, h1_bf, out, 64, N_ENT);
    layer_kernel<64, 32><<<(N_ENT + 3) / 4, 256, 0, stream>>>(
        h1_bf, W1_1, b1_1, W2_1, b2_1, row_ptr, att_csr, src_csr, h2_bf, out, 128, N_ENT);
    layer_kernel<32, 16><<<(N_ENT + 3) / 4, 256, 0, stream>>>(
        h2_bf, W1_2, b1_2, W2_2, b2_2, row_ptr, att_csr, src_csr, nullptr, out, 160, N_ENT);
}